// Round 6
// baseline (305.656 us; speedup 1.0000x reference)
//
#include <hip/hip_runtime.h>
#include <hip/hip_bf16.h>
#include <hip/hip_fp16.h>
#include <stdint.h>

// Problem constants (from reference)
#define DIM   512
#define NH    8
#define HD    64
#define NB    16
#define NTOK  1024
#define KHOPS 5

typedef __attribute__((ext_vector_type(8))) short bf16x8;   // 8 bf16 = 4 VGPR
typedef __attribute__((ext_vector_type(4))) float f32x4;

#define LOG2E 1.4426950408889634f

__device__ __forceinline__ unsigned short f32_to_bf16(float f) {
    unsigned int u = __builtin_bit_cast(unsigned int, f);
    unsigned int r = (u + 0x7FFFu + ((u >> 16) & 1u)) >> 16;   // RNE
    return (unsigned short)r;
}

__device__ __forceinline__ float fast_exp2(float x) {
    return __builtin_amdgcn_exp2f(x);
}

#define AS1C(p) ((const __attribute__((address_space(1))) void*)(p))
#define AS3(p)  ((__attribute__((address_space(3))) void*)(p))

// ---------------------------------------------------------------------------
// merged fp32 -> bf16 converts: x (8192 blocks), Wqkv (768), Wproj (256)
// ---------------------------------------------------------------------------
__global__ __launch_bounds__(256) void cvt_all(const float* __restrict__ x,
                                               const float* __restrict__ wq,
                                               const float* __restrict__ wp,
                                               unsigned short* __restrict__ xb,
                                               unsigned short* __restrict__ wqb,
                                               unsigned short* __restrict__ wpb) {
    int bid = blockIdx.x;
    const float* in; unsigned short* out; int i;
    if (bid < 8192)      { in = x;  out = xb;  i = bid * 256 + threadIdx.x; }
    else if (bid < 8960) { in = wq; out = wqb; i = (bid - 8192) * 256 + threadIdx.x; }
    else                 { in = wp; out = wpb; i = (bid - 8960) * 256 + threadIdx.x; }
    float4 v = reinterpret_cast<const float4*>(in)[i];
    ushort4 o;
    o.x = f32_to_bf16(v.x); o.y = f32_to_bf16(v.y);
    o.z = f32_to_bf16(v.z); o.w = f32_to_bf16(v.w);
    reinterpret_cast<ushort4*>(out)[i] = o;
}

// ---------------------------------------------------------------------------
// Fused hop-bias, ALL 8 HEADS per block. Along-j fp16 pair layout:
//   biast_u32[(h*1024 + i)*512 + (j>>1)] = half2(bias[i][j], bias[i][j+1])
// ---------------------------------------------------------------------------
__global__ __launch_bounds__(256) void bias_fused(const float* __restrict__ H,
                                                  const float* __restrict__ hop_logits,
                                                  const float* __restrict__ rel_alpha,
                                                  uint32_t* __restrict__ biast) {
    const int tid = threadIdx.x;
    const int jt = blockIdx.x, it = blockIdx.y;
    const int j0 = jt * 64, i0 = it * 64;
    float cf[NH][KHOPS];
#pragma unroll
    for (int h = 0; h < NH; ++h) {
        float m = -1e30f;
#pragma unroll
        for (int k = 0; k < KHOPS; ++k) m = fmaxf(m, hop_logits[h * KHOPS + k]);
        float s = 0.f;
#pragma unroll
        for (int k = 0; k < KHOPS; ++k) { cf[h][k] = fast_exp2((hop_logits[h * KHOPS + k] - m) * LOG2E); s += cf[h][k]; }
        float ra = rel_alpha[h] * LOG2E / s;
#pragma unroll
        for (int k = 0; k < KHOPS; ++k) cf[h][k] *= ra;
    }
    const int r = tid >> 2, c0 = (tid & 3) * 16;
    float hv[KHOPS][16];
#pragma unroll
    for (int k = 0; k < KHOPS; ++k) {
        const float4* src = reinterpret_cast<const float4*>(
            H + (size_t)k * 1048576 + (size_t)(i0 + r) * 1024 + j0 + c0);
#pragma unroll
        for (int q = 0; q < 4; ++q) {
            float4 v = src[q];
            hv[k][q * 4 + 0] = v.x; hv[k][q * 4 + 1] = v.y;
            hv[k][q * 4 + 2] = v.z; hv[k][q * 4 + 3] = v.w;
        }
    }
    for (int h = 0; h < NH; ++h) {
        uint32_t buf[8];
#pragma unroll
        for (int q = 0; q < 4; ++q) {
            float a0 = 0.f, a1 = 0.f, a2 = 0.f, a3 = 0.f;
#pragma unroll
            for (int k = 0; k < KHOPS; ++k) {
                a0 += cf[h][k] * hv[k][q * 4 + 0];
                a1 += cf[h][k] * hv[k][q * 4 + 1];
                a2 += cf[h][k] * hv[k][q * 4 + 2];
                a3 += cf[h][k] * hv[k][q * 4 + 3];
            }
            buf[q * 2 + 0] = __builtin_bit_cast(uint32_t, __floats2half2_rn(a0, a1));
            buf[q * 2 + 1] = __builtin_bit_cast(uint32_t, __floats2half2_rn(a2, a3));
        }
        uint32_t* dst = biast + ((size_t)h * 1024 + i0 + r) * 512 + ((j0 + c0) >> 1);
        uint4 w0; w0.x = buf[0]; w0.y = buf[1]; w0.z = buf[2]; w0.w = buf[3];
        uint4 w1; w1.x = buf[4]; w1.y = buf[5]; w1.z = buf[6]; w1.w = buf[7];
        reinterpret_cast<uint4*>(dst)[0] = w0;
        reinterpret_cast<uint4*>(dst)[1] = w1;
    }
}

// ---------------------------------------------------------------------------
// gemm_qkv v2: 2-phase double-buffered prefetch (T3 minimum-2-phase recipe).
// Per iter: issue STAGE(buf^1, k+1) FIRST, then ds_read+MFMA from buf[cur],
// then ONE __syncthreads (its vmcnt(0) drain lands a full compute phase
// after issue). Old version was fully serialized (stage; barrier; compute).
// XCD-partitioned grid; V column-blocks written transposed into vt.
// ---------------------------------------------------------------------------
__global__ __launch_bounds__(256) void gemm_qkv(const unsigned short* __restrict__ A,
                                                const unsigned short* __restrict__ Bw,
                                                unsigned short* __restrict__ qkv,
                                                unsigned short* __restrict__ vt) {
    __shared__ unsigned short As[2][128 * 32];
    __shared__ unsigned short Bs[2][128 * 32];
    const int tid  = threadIdx.x;
    const int lane = tid & 63;
    const int w    = tid >> 6;
    const int wr   = (w >> 1) * 64, wc = (w & 1) * 64;
    const int l15  = lane & 15, quad = lane >> 4;
    const int bid  = blockIdx.x;
    const int xcd  = bid & 7, slot = bid >> 3;
    const int m0   = (xcd * 16 + (slot & 15)) * 128;
    const int n0   = (slot >> 4) * 128;
    const int K = 512, Nn = 1536;

    const int sc = w * 64 + lane;                 // 0..255
    const int sr = sc >> 2, skh = sc & 3;         // row 0..127, 8-short chunk 0..3
    const unsigned short* gaB = A  + (size_t)(m0 + sr) * K + skh * 8;
    const unsigned short* gbB = Bw + (size_t)(n0 + sr) * K + skh * 8;
    const unsigned short* gaB2 = A  + (size_t)(m0 + 64 + sr) * K + skh * 8;
    const unsigned short* gbB2 = Bw + (size_t)(n0 + 64 + sr) * K + skh * 8;

#define STAGE_QKV(buf, k0s)                                                              \
    do {                                                                                 \
        __builtin_amdgcn_global_load_lds(AS1C(gaB  + (k0s)), AS3(&As[buf][sc * 8]), 16, 0, 0);          \
        __builtin_amdgcn_global_load_lds(AS1C(gbB  + (k0s)), AS3(&Bs[buf][sc * 8]), 16, 0, 0);          \
        __builtin_amdgcn_global_load_lds(AS1C(gaB2 + (k0s)), AS3(&As[buf][(256 + sc) * 8]), 16, 0, 0);  \
        __builtin_amdgcn_global_load_lds(AS1C(gbB2 + (k0s)), AS3(&Bs[buf][(256 + sc) * 8]), 16, 0, 0);  \
    } while (0)

    f32x4 acc[4][4];
#pragma unroll
    for (int i = 0; i < 4; ++i)
#pragma unroll
        for (int j = 0; j < 4; ++j) { acc[i][j][0] = 0.f; acc[i][j][1] = 0.f; acc[i][j][2] = 0.f; acc[i][j][3] = 0.f; }

    STAGE_QKV(0, 0);
    __syncthreads();                // tile 0 staged
    int cur = 0;
    for (int k0 = 0; k0 < K; k0 += 32) {
        if (k0 + 32 < K) STAGE_QKV(cur ^ 1, k0 + 32);    // issue next FIRST
        bf16x8 af[4], bfr[4];
#pragma unroll
        for (int rt = 0; rt < 4; ++rt)
            af[rt] = *reinterpret_cast<const bf16x8*>(&As[cur][(wr + rt * 16 + l15) * 32 + quad * 8]);
#pragma unroll
        for (int ct = 0; ct < 4; ++ct)
            bfr[ct] = *reinterpret_cast<const bf16x8*>(&Bs[cur][(wc + ct * 16 + l15) * 32 + quad * 8]);
#pragma unroll
        for (int rt = 0; rt < 4; ++rt)
#pragma unroll
            for (int ct = 0; ct < 4; ++ct)
                acc[rt][ct] = __builtin_amdgcn_mfma_f32_16x16x32_bf16(af[rt], bfr[ct], acc[rt][ct], 0, 0, 0);
        __syncthreads();            // drains prefetch (issued a full phase ago); frees buf[cur]
        cur ^= 1;
    }
#undef STAGE_QKV

    if (n0 < 1024) {
        // Q/K: row-major bf16 into qkv
#pragma unroll
        for (int rt = 0; rt < 4; ++rt)
#pragma unroll
            for (int ct = 0; ct < 4; ++ct)
#pragma unroll
                for (int reg = 0; reg < 4; ++reg) {
                    int row = m0 + wr + rt * 16 + quad * 4 + reg;
                    int col = n0 + wc + ct * 16 + l15;
                    qkv[(size_t)row * Nn + col] = f32_to_bf16(acc[rt][ct][reg]);
                }
    } else {
        // V: transposed into vt[b][h][d][token]
        const int b = m0 >> 10;
#pragma unroll
        for (int ct = 0; ct < 4; ++ct) {
            int c = n0 - 1024 + wc + ct * 16 + l15;   // h*64+d
            unsigned short* vrow = vt + ((size_t)(b * 8) * 64 + c) * 1024;
#pragma unroll
            for (int rt = 0; rt < 4; ++rt) {
                int trow = (m0 & 1023) + wr + rt * 16 + quad * 4;
                ushort4 pk;
                pk.x = f32_to_bf16(acc[rt][ct][0]);
                pk.y = f32_to_bf16(acc[rt][ct][1]);
                pk.z = f32_to_bf16(acc[rt][ct][2]);
                pk.w = f32_to_bf16(acc[rt][ct][3]);
                *reinterpret_cast<ushort4*>(vrow + trow) = pk;
            }
        }
    }
}

// ---------------------------------------------------------------------------
// gemm_proj v2: same 2-phase prefetch structure. fp32 out + bias.
// ---------------------------------------------------------------------------
__global__ __launch_bounds__(256) void gemm_proj(const unsigned short* __restrict__ A,
                                                 const unsigned short* __restrict__ Bw,
                                                 float* __restrict__ C,
                                                 const float* __restrict__ cbias) {
    __shared__ unsigned short As[2][128 * 32];
    __shared__ unsigned short Bs[2][128 * 32];
    const int tid  = threadIdx.x;
    const int lane = tid & 63;
    const int w    = tid >> 6;
    const int wr   = (w >> 1) * 64, wc = (w & 1) * 64;
    const int l15  = lane & 15, quad = lane >> 4;
    const int bid  = blockIdx.x;
    const int xcd  = bid & 7, slot = bid >> 3;
    const int m0   = (xcd * 16 + (slot & 15)) * 128;
    const int n0   = (slot >> 4) * 128;
    const int K = 512, Nn = 512;

    const int sc = w * 64 + lane;
    const int sr = sc >> 2, skh = sc & 3;
    const unsigned short* gaB  = A  + (size_t)(m0 + sr) * K + skh * 8;
    const unsigned short* gbB  = Bw + (size_t)(n0 + sr) * K + skh * 8;
    const unsigned short* gaB2 = A  + (size_t)(m0 + 64 + sr) * K + skh * 8;
    const unsigned short* gbB2 = Bw + (size_t)(n0 + 64 + sr) * K + skh * 8;

#define STAGE_PRJ(buf, k0s)                                                              \
    do {                                                                                 \
        __builtin_amdgcn_global_load_lds(AS1C(gaB  + (k0s)), AS3(&As[buf][sc * 8]), 16, 0, 0);          \
        __builtin_amdgcn_global_load_lds(AS1C(gbB  + (k0s)), AS3(&Bs[buf][sc * 8]), 16, 0, 0);          \
        __builtin_amdgcn_global_load_lds(AS1C(gaB2 + (k0s)), AS3(&As[buf][(256 + sc) * 8]), 16, 0, 0);  \
        __builtin_amdgcn_global_load_lds(AS1C(gbB2 + (k0s)), AS3(&Bs[buf][(256 + sc) * 8]), 16, 0, 0);  \
    } while (0)

    f32x4 acc[4][4];
#pragma unroll
    for (int i = 0; i < 4; ++i)
#pragma unroll
        for (int j = 0; j < 4; ++j) { acc[i][j][0] = 0.f; acc[i][j][1] = 0.f; acc[i][j][2] = 0.f; acc[i][j][3] = 0.f; }

    STAGE_PRJ(0, 0);
    __syncthreads();
    int cur = 0;
    for (int k0 = 0; k0 < K; k0 += 32) {
        if (k0 + 32 < K) STAGE_PRJ(cur ^ 1, k0 + 32);
        bf16x8 af[4], bfr[4];
#pragma unroll
        for (int rt = 0; rt < 4; ++rt)
            af[rt] = *reinterpret_cast<const bf16x8*>(&As[cur][(wr + rt * 16 + l15) * 32 + quad * 8]);
#pragma unroll
        for (int ct = 0; ct < 4; ++ct)
            bfr[ct] = *reinterpret_cast<const bf16x8*>(&Bs[cur][(wc + ct * 16 + l15) * 32 + quad * 8]);
#pragma unroll
        for (int rt = 0; rt < 4; ++rt)
#pragma unroll
            for (int ct = 0; ct < 4; ++ct)
                acc[rt][ct] = __builtin_amdgcn_mfma_f32_16x16x32_bf16(af[rt], bfr[ct], acc[rt][ct], 0, 0, 0);
        __syncthreads();
        cur ^= 1;
    }
#undef STAGE_PRJ

#pragma unroll
    for (int ct = 0; ct < 4; ++ct) {
        int col = n0 + wc + ct * 16 + l15;
        float bv = cbias[col];
#pragma unroll
        for (int rt = 0; rt < 4; ++rt)
#pragma unroll
            for (int reg = 0; reg < 4; ++reg) {
                int row = m0 + wr + rt * 16 + quad * 4 + reg;
                C[(size_t)row * Nn + col] = acc[rt][ct][reg] + bv;
            }
    }
}

// ---------------------------------------------------------------------------
// Flash attention v11: v10 + bias prefetched ONE TILE AHEAD into registers.
// The 8 bias loads (L2/L3, ~600 cyc) were issued at the top of each tile and
// consumed right after QK^T -> on the serial chain. Now tile it+1's bias is
// issued alongside the K/V prefetch and consumed a full tile later.
// +16 VGPR (blc), ~96 total, under the (512,2) 128-VGPR cap -> no spill.
// Everything else identical to v10 (verified absmax == baseline).
// ---------------------------------------------------------------------------
__global__ __launch_bounds__(512, 2) void flash_attn(const unsigned short* __restrict__ qkv,
                                                     const unsigned short* __restrict__ vt,
                                                     const uint32_t* __restrict__ biast,
                                                     unsigned short* __restrict__ aout) {
    __shared__ unsigned short Kb[2][64 * 64];
    __shared__ unsigned short Vb[2][64 * 64];
    __shared__ __align__(16) unsigned short Ps[8 * 32 * 64];
    const int tid  = threadIdx.x;
    const int lane = tid & 63, w = tid >> 6;            // w in 0..7
    const int l15  = lane & 15, quad = lane >> 4;
    const int h = blockIdx.x, qt = blockIdx.y, b = blockIdx.z;   // x=h: XCD locality
    const int i0 = qt * 256 + w * 32;                   // 8 waves x 32 queries
    const float kscale = 0.125f * LOG2E;
    const int l7 = l15 & 7;
    const int psw = l7 << 3;                            // Ps XOR swizzle (shorts)

    // Q fragments: A[m=lane&15][k=quad*8+j]
    bf16x8 qf[2][2];
#pragma unroll
    for (int rt = 0; rt < 2; ++rt)
#pragma unroll
        for (int ks = 0; ks < 2; ++ks)
            qf[rt][ks] = *reinterpret_cast<const bf16x8*>(
                qkv + (size_t)(b * 1024 + i0 + rt * 16 + l15) * 1536 + h * 64 + ks * 32 + quad * 8);

    f32x4 o[2][4];
    f32x4 lacc[2];
#pragma unroll
    for (int rt = 0; rt < 2; ++rt) {
#pragma unroll
        for (int nt = 0; nt < 4; ++nt) { o[rt][nt][0] = 0.f; o[rt][nt][1] = 0.f; o[rt][nt][2] = 0.f; o[rt][nt][3] = 0.f; }
        lacc[rt][0] = 0.f; lacc[rt][1] = 0.f; lacc[rt][2] = 0.f; lacc[rt][3] = 0.f;
    }

    bf16x8 ones;
#pragma unroll
    for (int e = 0; e < 8; ++e) ones[e] = (short)0x3F80;   // bf16 1.0

    const int srow = lane >> 3;
    const int gch  = (lane & 7) ^ srow;
    const unsigned short* kgbase = qkv + (size_t)b * 1024 * 1536 + 512 + h * 64 + gch * 8;
    const unsigned short* vgbase = vt + (size_t)((b * 8 + h) * 64) * 1024 + gch * 8;
    // bias base: biast_u32[(h*1024 + i)*512 + (j>>1)]; this wave's query rows
    const uint32_t* bb = biast + ((size_t)h * 1024 + i0) * 512;
    unsigned short* ps = &Ps[w * 32 * 64];

    // prologue: stage tile 0 into buffer 0 (each wave: 8 K-rows + 8 V-rows)
    {
        int rl = w * 8 + srow;
        __builtin_amdgcn_global_load_lds(AS1C(kgbase + (size_t)rl * 1536),
                                         AS3(&Kb[0][(w * 8) * 64]), 16, 0, 0);
        __builtin_amdgcn_global_load_lds(AS1C(vgbase + (size_t)rl * 1024),
                                         AS3(&Vb[0][(w * 8) * 64]), 16, 0, 0);
    }
    // prologue: bias for tile 0 into registers
    uint2 blc[2][4];
#pragma unroll
    for (int rt = 0; rt < 2; ++rt)
#pragma unroll
        for (int jt = 0; jt < 4; ++jt)
            blc[rt][jt] = *reinterpret_cast<const uint2*>(
                bb + (size_t)(rt * 16 + l15) * 512 + jt * 8 + quad * 2);

#pragma unroll 2
    for (int it = 0; it < 16; ++it) {
        const int cur = it & 1, nxt = cur ^ 1;
        const int j0 = it * 64;
        __syncthreads();   // drains prefetch (issued a full compute phase ago); frees buf[nxt]

        if (it < 15) {
            const int j0n = j0 + 64;
            int rl = w * 8 + srow;
            __builtin_amdgcn_global_load_lds(AS1C(kgbase + (size_t)(j0n + rl) * 1536),
                                             AS3(&Kb[nxt][(w * 8) * 64]), 16, 0, 0);
            __builtin_amdgcn_global_load_lds(AS1C(vgbase + (size_t)rl * 1024 + j0n),
                                             AS3(&Vb[nxt][(w * 8) * 64]), 16, 0, 0);
        }

        // prefetch NEXT tile's bias (consumed a full tile later); last iter
        // re-loads tile 0 (valid, cached, unused) to stay branch-free.
        const int j0p = (it < 15) ? ((j0 + 64) >> 1) : 0;
        uint2 bln[2][4];
#pragma unroll
        for (int rt = 0; rt < 2; ++rt)
#pragma unroll
            for (int jt = 0; jt < 4; ++jt)
                bln[rt][jt] = *reinterpret_cast<const uint2*>(
                    bb + (size_t)(rt * 16 + l15) * 512 + j0p + jt * 8 + quad * 2);

        // S^T = K Q^T: D[key = quad*4+reg (+jt*16)][query = l15 (+rt*16)]
        f32x4 s[2][4];
#pragma unroll
        for (int rt = 0; rt < 2; ++rt)
#pragma unroll
            for (int jt = 0; jt < 4; ++jt) { s[rt][jt][0] = 0.f; s[rt][jt][1] = 0.f; s[rt][jt][2] = 0.f; s[rt][jt][3] = 0.f; }
        __builtin_amdgcn_s_setprio(1);
#pragma unroll
        for (int ks = 0; ks < 2; ++ks) {
            bf16x8 kf[4];
#pragma unroll
            for (int jt = 0; jt < 4; ++jt)
                kf[jt] = *reinterpret_cast<const bf16x8*>(
                    &Kb[cur][(jt * 16 + l15) * 64 + (((ks * 4 + quad) ^ l7) * 8)]);
#pragma unroll
            for (int rt = 0; rt < 2; ++rt)
#pragma unroll
                for (int jt = 0; jt < 4; ++jt)
                    s[rt][jt] = __builtin_amdgcn_mfma_f32_16x16x32_bf16(kf[jt], qf[rt][ks], s[rt][jt], 0, 0, 0);
        }
        __builtin_amdgcn_s_setprio(0);

        // p = exp2(s*kscale + bias_cur); manual RNE pack -> ds_write_b64
#pragma unroll
        for (int rt = 0; rt < 2; ++rt)
#pragma unroll
            for (int jt = 0; jt < 4; ++jt) {
                float2 f0 = __half22float2(__builtin_bit_cast(__half2, blc[rt][jt].x));
                float2 f1 = __half22float2(__builtin_bit_cast(__half2, blc[rt][jt].y));
                float p0 = fast_exp2(__builtin_fmaf(s[rt][jt][0], kscale, f0.x));
                float p1 = fast_exp2(__builtin_fmaf(s[rt][jt][1], kscale, f0.y));
                float p2 = fast_exp2(__builtin_fmaf(s[rt][jt][2], kscale, f1.x));
                float p3 = fast_exp2(__builtin_fmaf(s[rt][jt][3], kscale, f1.y));
                uint32_t u0 = (uint32_t)f32_to_bf16(p0) | ((uint32_t)f32_to_bf16(p1) << 16);
                uint32_t u1 = (uint32_t)f32_to_bf16(p2) | ((uint32_t)f32_to_bf16(p3) << 16);
                uint2 pk; pk.x = u0; pk.y = u1;
                *reinterpret_cast<uint2*>(
                    ps + (((rt * 16 + l15) * 64 + jt * 16 + quad * 4) ^ psw)) = pk;
            }

        // PV + row-sum (same-wave Ps round trip; no barrier needed)
        __builtin_amdgcn_s_setprio(1);
#pragma unroll
        for (int ks = 0; ks < 2; ++ks) {
            bf16x8 pf[2], vf[4];
#pragma unroll
            for (int rt = 0; rt < 2; ++rt)
                pf[rt] = *reinterpret_cast<const bf16x8*>(
                    ps + (((rt * 16 + l15) * 64 + ks * 32 + quad * 8) ^ psw));
#pragma unroll
            for (int nt = 0; nt < 4; ++nt)
                vf[nt] = *reinterpret_cast<const bf16x8*>(
                    &Vb[cur][(nt * 16 + l15) * 64 + (((ks * 4 + quad) ^ l7) * 8)]);
#pragma unroll
            for (int rt = 0; rt < 2; ++rt) {
#pragma unroll
                for (int nt = 0; nt < 4; ++nt)
                    o[rt][nt] = __builtin_amdgcn_mfma_f32_16x16x32_bf16(pf[rt], vf[nt], o[rt][nt], 0, 0, 0);
                lacc[rt] = __builtin_amdgcn_mfma_f32_16x16x32_bf16(pf[rt], ones, lacc[rt], 0, 0, 0);
            }
        }
        __builtin_amdgcn_s_setprio(0);

        // rotate bias registers
#pragma unroll
        for (int rt = 0; rt < 2; ++rt)
#pragma unroll
            for (int jt = 0; jt < 4; ++jt)
                blc[rt][jt] = bln[rt][jt];
    }

    // finalize
#pragma unroll
    for (int rt = 0; rt < 2; ++rt) {
        float inv[4];
#pragma unroll
        for (int reg = 0; reg < 4; ++reg) inv[reg] = 1.f / lacc[rt][reg];
#pragma unroll
        for (int nt = 0; nt < 4; ++nt)
#pragma unroll
            for (int reg = 0; reg < 4; ++reg) {
                int row = b * 1024 + i0 + rt * 16 + quad * 4 + reg;
                int col = h * 64 + nt * 16 + l15;
                aout[(size_t)row * 512 + col] = f32_to_bf16(o[rt][nt][reg] * inv[reg]);
            }
    }
}

// ---------------------------------------------------------------------------
extern "C" void kernel_launch(void* const* d_in, const int* in_sizes, int n_in,
                              void* d_out, int out_size, void* d_ws, size_t ws_size,
                              hipStream_t stream) {
    const float* x          = (const float*)d_in[0];
    const float* Hstack     = (const float*)d_in[1];
    const float* hop_logits = (const float*)d_in[2];
    const float* rel_alpha  = (const float*)d_in[3];
    const float* Wqkv       = (const float*)d_in[4];
    const float* Wproj      = (const float*)d_in[5];
    const float* bproj      = (const float*)d_in[6];
    float* out = (float*)d_out;

    char* ws = (char*)d_ws;
    unsigned short* xb    = (unsigned short*)(ws);                  // x bf16        16 MB
    unsigned short* wqb   = (unsigned short*)(ws + 16777216);       // Wqkv bf16    1.5 MB
    unsigned short* wpb   = (unsigned short*)(ws + 18350080);       // Wproj bf16   0.5 MB
    unsigned short* qkvb  = (unsigned short*)(ws + 18874368);       // qkv bf16 (Q,K used)  48 MB
    unsigned short* vtb   = (unsigned short*)(ws + 69206016);       // V^T bf16      16 MB
    uint32_t*       biast = (uint32_t*)(ws + 85983232);             // bias fp16 [h][i][j/2] 16 MB
    unsigned short* aoutb = (unsigned short*)(ws + 102760448);      // attn out bf16 16 MB

    // 1. merged converts
    cvt_all<<<9216, 256, 0, stream>>>(x, Wqkv, Wproj, xb, wqb, wpb);

    // 2. fused hop-bias (all heads per block) -> fp16 along-j bias layout
    bias_fused<<<dim3(16, 16), 256, 0, stream>>>(Hstack, hop_logits, rel_alpha, biast);

    // 3. qkv GEMM (2-phase prefetch, XCD-partitioned); V written transposed
    gemm_qkv<<<1536, 256, 0, stream>>>(xb, wqb, qkvb, vtb);

    // 4. flash attention (8-wave, dbuf K/V, bias reg-prefetch) -> [B,N,512] bf16
    flash_attn<<<dim3(8, 4, 16), 512, 0, stream>>>(qkvb, vtb, biast, aoutb);

    // 5. out = attn_out @ Wproj^T + bproj (2-phase prefetch, XCD-partitioned)
    gemm_proj<<<512, 256, 0, stream>>>(aoutb, wpb, out, bproj);
}

// Round 8
// 275.029 us; speedup vs baseline: 1.1114x; 1.1114x over previous
//
#include <hip/hip_runtime.h>
#include <hip/hip_bf16.h>
#include <hip/hip_fp16.h>
#include <stdint.h>

// Problem constants (from reference)
#define DIM   512
#define NH    8
#define HD    64
#define NB    16
#define NTOK  1024
#define KHOPS 5

typedef __attribute__((ext_vector_type(8))) short bf16x8;   // 8 bf16 = 4 VGPR
typedef __attribute__((ext_vector_type(4))) float f32x4;

#define LOG2E 1.4426950408889634f

__device__ __forceinline__ unsigned short f32_to_bf16(float f) {
    unsigned int u = __builtin_bit_cast(unsigned int, f);
    unsigned int r = (u + 0x7FFFu + ((u >> 16) & 1u)) >> 16;   // RNE
    return (unsigned short)r;
}

__device__ __forceinline__ float fast_exp2(float x) {
    return __builtin_amdgcn_exp2f(x);
}

#define AS1C(p) ((const __attribute__((address_space(1))) void*)(p))
#define AS3(p)  ((__attribute__((address_space(3))) void*)(p))

// ---------------------------------------------------------------------------
// merged cvt + hop-bias kernel (one dispatch, grid-partitioned):
//   bid < 9216 : fp32->bf16 converts x (8192), Wqkv (768), Wproj (256)
//   bid >= 9216: hop-bias blocks (256 = 16x16 tiles)
// bias layout: biast_u32[(h*1024 + i)*512 + (j>>1)] = half2(bias[i][j], b[i][j+1])
// ---------------------------------------------------------------------------
__global__ __launch_bounds__(256) void cvt_bias(const float* __restrict__ x,
                                                const float* __restrict__ wq,
                                                const float* __restrict__ wp,
                                                const float* __restrict__ H,
                                                const float* __restrict__ hop_logits,
                                                const float* __restrict__ rel_alpha,
                                                unsigned short* __restrict__ xb,
                                                unsigned short* __restrict__ wqb,
                                                unsigned short* __restrict__ wpb,
                                                uint32_t* __restrict__ biast) {
    const int bid = blockIdx.x;
    const int tid = threadIdx.x;
    if (bid < 9216) {
        const float* in; unsigned short* out; int i;
        if (bid < 8192)      { in = x;  out = xb;  i = bid * 256 + tid; }
        else if (bid < 8960) { in = wq; out = wqb; i = (bid - 8192) * 256 + tid; }
        else                 { in = wp; out = wpb; i = (bid - 8960) * 256 + tid; }
        float4 v = reinterpret_cast<const float4*>(in)[i];
        ushort4 o;
        o.x = f32_to_bf16(v.x); o.y = f32_to_bf16(v.y);
        o.z = f32_to_bf16(v.z); o.w = f32_to_bf16(v.w);
        reinterpret_cast<ushort4*>(out)[i] = o;
        return;
    }
    const int bb = bid - 9216;
    const int jt = bb & 15, it = bb >> 4;
    const int j0 = jt * 64, i0 = it * 64;
    float cf[NH][KHOPS];
#pragma unroll
    for (int h = 0; h < NH; ++h) {
        float m = -1e30f;
#pragma unroll
        for (int k = 0; k < KHOPS; ++k) m = fmaxf(m, hop_logits[h * KHOPS + k]);
        float s = 0.f;
#pragma unroll
        for (int k = 0; k < KHOPS; ++k) { cf[h][k] = fast_exp2((hop_logits[h * KHOPS + k] - m) * LOG2E); s += cf[h][k]; }
        float ra = rel_alpha[h] * LOG2E / s;
#pragma unroll
        for (int k = 0; k < KHOPS; ++k) cf[h][k] *= ra;
    }
    const int r = tid >> 2, c0 = (tid & 3) * 16;
    float hv[KHOPS][16];
#pragma unroll
    for (int k = 0; k < KHOPS; ++k) {
        const float4* src = reinterpret_cast<const float4*>(
            H + (size_t)k * 1048576 + (size_t)(i0 + r) * 1024 + j0 + c0);
#pragma unroll
        for (int q = 0; q < 4; ++q) {
            float4 v = src[q];
            hv[k][q * 4 + 0] = v.x; hv[k][q * 4 + 1] = v.y;
            hv[k][q * 4 + 2] = v.z; hv[k][q * 4 + 3] = v.w;
        }
    }
    for (int h = 0; h < NH; ++h) {
        uint32_t buf[8];
#pragma unroll
        for (int q = 0; q < 4; ++q) {
            float a0 = 0.f, a1 = 0.f, a2 = 0.f, a3 = 0.f;
#pragma unroll
            for (int k = 0; k < KHOPS; ++k) {
                a0 += cf[h][k] * hv[k][q * 4 + 0];
                a1 += cf[h][k] * hv[k][q * 4 + 1];
                a2 += cf[h][k] * hv[k][q * 4 + 2];
                a3 += cf[h][k] * hv[k][q * 4 + 3];
            }
            buf[q * 2 + 0] = __builtin_bit_cast(uint32_t, __floats2half2_rn(a0, a1));
            buf[q * 2 + 1] = __builtin_bit_cast(uint32_t, __floats2half2_rn(a2, a3));
        }
        uint32_t* dst = biast + ((size_t)h * 1024 + i0 + r) * 512 + ((j0 + c0) >> 1);
        uint4 w0; w0.x = buf[0]; w0.y = buf[1]; w0.z = buf[2]; w0.w = buf[3];
        uint4 w1; w1.x = buf[4]; w1.y = buf[5]; w1.z = buf[6]; w1.w = buf[7];
        reinterpret_cast<uint4*>(dst)[0] = w0;
        reinterpret_cast<uint4*>(dst)[1] = w1;
    }
}

// ---------------------------------------------------------------------------
// gemm_qkv v3: proven 2-barrier structure (stage -> barrier -> compute), with
//  - BK=64: 8 K-iterations instead of 16 (half the vmcnt-drain barriers).
//  - XOR-swizzled staging (pre-swizzled GLOBAL src, linear LDS dest; read
//    chunk g at ((g ^ (row&7))*8) -- same verified pattern as flash K-stage.
//    BK=64's 128B row stride would otherwise 16-way bank-conflict ds_read_b128.
//  - Q/K path: swapped-operand MFMA (acc_T = mfma(B,A)) so a thread's 4 regs
//    = 4 consecutive cols -> ushort4 C-stores (16 wide vs 64 scalar).
//  - V path: original order, row-packed ushort4 into vt (unchanged).
// XCD-partitioned grid as before.
// ---------------------------------------------------------------------------
__global__ __launch_bounds__(256) void gemm_qkv(const unsigned short* __restrict__ A,
                                                const unsigned short* __restrict__ Bw,
                                                unsigned short* __restrict__ qkv,
                                                unsigned short* __restrict__ vt) {
    __shared__ unsigned short As[128 * 64];
    __shared__ unsigned short Bs[128 * 64];
    const int tid  = threadIdx.x;
    const int lane = tid & 63;
    const int w    = tid >> 6;
    const int wr   = (w >> 1) * 64, wc = (w & 1) * 64;
    const int l15  = lane & 15, quad = lane >> 4;
    const int bid  = blockIdx.x;
    const int xcd  = bid & 7, slot = bid >> 3;
    const int m0   = (xcd * 16 + (slot & 15)) * 128;
    const int n0   = (slot >> 4) * 128;
    const int K = 512, Nn = 1536;
    const int rA = l15 & 7;                      // row&7 for frag reads (row = ..+l15)

    f32x4 acc[4][4];
#pragma unroll
    for (int i = 0; i < 4; ++i)
#pragma unroll
        for (int j = 0; j < 4; ++j) { acc[i][j][0] = 0.f; acc[i][j][1] = 0.f; acc[i][j][2] = 0.f; acc[i][j][3] = 0.f; }

    if (n0 < 1024) {
        // ---- Q/K path: swapped operands, acc[ct][rt], vectorized C-store ----
        for (int k0 = 0; k0 < K; k0 += 64) {
            __syncthreads();
#pragma unroll
            for (int t = 0; t < 4; ++t) {
                int c = t * 256 + tid;               // 0..1023
                int row = c >> 3, ch = c & 7;
                int gch = ch ^ (row & 7);            // pre-swizzled global chunk
                __builtin_amdgcn_global_load_lds(AS1C(A  + (size_t)(m0 + row) * K + k0 + gch * 8),
                                                 AS3(&As[c * 8]), 16, 0, 0);
                __builtin_amdgcn_global_load_lds(AS1C(Bw + (size_t)(n0 + row) * K + k0 + gch * 8),
                                                 AS3(&Bs[c * 8]), 16, 0, 0);
            }
            __syncthreads();
#pragma unroll
            for (int ks = 0; ks < 2; ++ks) {
                bf16x8 af[4], bfr[4];
#pragma unroll
                for (int rt = 0; rt < 4; ++rt)
                    af[rt] = *reinterpret_cast<const bf16x8*>(
                        &As[(wr + rt * 16 + l15) * 64 + (((ks * 4 + quad) ^ rA) * 8)]);
#pragma unroll
                for (int ct = 0; ct < 4; ++ct)
                    bfr[ct] = *reinterpret_cast<const bf16x8*>(
                        &Bs[(wc + ct * 16 + l15) * 64 + (((ks * 4 + quad) ^ rA) * 8)]);
#pragma unroll
                for (int ct = 0; ct < 4; ++ct)
#pragma unroll
                    for (int rt = 0; rt < 4; ++rt)
                        acc[ct][rt] = __builtin_amdgcn_mfma_f32_16x16x32_bf16(bfr[ct], af[rt], acc[ct][rt], 0, 0, 0);
            }
        }
        // C[m0+wr+rt*16+l15][n0+wc+ct*16+quad*4+reg] = acc[ct][rt][reg]
#pragma unroll
        for (int rt = 0; rt < 4; ++rt) {
            int row = m0 + wr + rt * 16 + l15;
#pragma unroll
            for (int ct = 0; ct < 4; ++ct) {
                int col = n0 + wc + ct * 16 + quad * 4;
                ushort4 pk;
                pk.x = f32_to_bf16(acc[ct][rt][0]);
                pk.y = f32_to_bf16(acc[ct][rt][1]);
                pk.z = f32_to_bf16(acc[ct][rt][2]);
                pk.w = f32_to_bf16(acc[ct][rt][3]);
                *reinterpret_cast<ushort4*>(qkv + (size_t)row * Nn + col) = pk;
            }
        }
    } else {
        // ---- V path: original order, transposed row-packed store into vt ----
        for (int k0 = 0; k0 < K; k0 += 64) {
            __syncthreads();
#pragma unroll
            for (int t = 0; t < 4; ++t) {
                int c = t * 256 + tid;
                int row = c >> 3, ch = c & 7;
                int gch = ch ^ (row & 7);
                __builtin_amdgcn_global_load_lds(AS1C(A  + (size_t)(m0 + row) * K + k0 + gch * 8),
                                                 AS3(&As[c * 8]), 16, 0, 0);
                __builtin_amdgcn_global_load_lds(AS1C(Bw + (size_t)(n0 + row) * K + k0 + gch * 8),
                                                 AS3(&Bs[c * 8]), 16, 0, 0);
            }
            __syncthreads();
#pragma unroll
            for (int ks = 0; ks < 2; ++ks) {
                bf16x8 af[4], bfr[4];
#pragma unroll
                for (int rt = 0; rt < 4; ++rt)
                    af[rt] = *reinterpret_cast<const bf16x8*>(
                        &As[(wr + rt * 16 + l15) * 64 + (((ks * 4 + quad) ^ rA) * 8)]);
#pragma unroll
                for (int ct = 0; ct < 4; ++ct)
                    bfr[ct] = *reinterpret_cast<const bf16x8*>(
                        &Bs[(wc + ct * 16 + l15) * 64 + (((ks * 4 + quad) ^ rA) * 8)]);
#pragma unroll
                for (int rt = 0; rt < 4; ++rt)
#pragma unroll
                    for (int ct = 0; ct < 4; ++ct)
                        acc[rt][ct] = __builtin_amdgcn_mfma_f32_16x16x32_bf16(af[rt], bfr[ct], acc[rt][ct], 0, 0, 0);
            }
        }
        const int b = m0 >> 10;
#pragma unroll
        for (int ct = 0; ct < 4; ++ct) {
            int c = n0 - 1024 + wc + ct * 16 + l15;   // h*64+d
            unsigned short* vrow = vt + ((size_t)(b * 8) * 64 + c) * 1024;
#pragma unroll
            for (int rt = 0; rt < 4; ++rt) {
                int trow = (m0 & 1023) + wr + rt * 16 + quad * 4;
                ushort4 pk;
                pk.x = f32_to_bf16(acc[rt][ct][0]);
                pk.y = f32_to_bf16(acc[rt][ct][1]);
                pk.z = f32_to_bf16(acc[rt][ct][2]);
                pk.w = f32_to_bf16(acc[rt][ct][3]);
                *reinterpret_cast<ushort4*>(vrow + trow) = pk;
            }
        }
    }
}

// ---------------------------------------------------------------------------
// gemm_proj v3: same BK=64 + swizzle + swapped-operand epilogue; float4 out.
// ---------------------------------------------------------------------------
__global__ __launch_bounds__(256) void gemm_proj(const unsigned short* __restrict__ A,
                                                 const unsigned short* __restrict__ Bw,
                                                 float* __restrict__ C,
                                                 const float* __restrict__ cbias) {
    __shared__ unsigned short As[128 * 64];
    __shared__ unsigned short Bs[128 * 64];
    const int tid  = threadIdx.x;
    const int lane = tid & 63;
    const int w    = tid >> 6;
    const int wr   = (w >> 1) * 64, wc = (w & 1) * 64;
    const int l15  = lane & 15, quad = lane >> 4;
    const int bid  = blockIdx.x;
    const int xcd  = bid & 7, slot = bid >> 3;
    const int m0   = (xcd * 16 + (slot & 15)) * 128;
    const int n0   = (slot >> 4) * 128;
    const int K = 512, Nn = 512;
    const int rA = l15 & 7;

    f32x4 acc[4][4];
#pragma unroll
    for (int i = 0; i < 4; ++i)
#pragma unroll
        for (int j = 0; j < 4; ++j) { acc[i][j][0] = 0.f; acc[i][j][1] = 0.f; acc[i][j][2] = 0.f; acc[i][j][3] = 0.f; }

    for (int k0 = 0; k0 < K; k0 += 64) {
        __syncthreads();
#pragma unroll
        for (int t = 0; t < 4; ++t) {
            int c = t * 256 + tid;
            int row = c >> 3, ch = c & 7;
            int gch = ch ^ (row & 7);
            __builtin_amdgcn_global_load_lds(AS1C(A  + (size_t)(m0 + row) * K + k0 + gch * 8),
                                             AS3(&As[c * 8]), 16, 0, 0);
            __builtin_amdgcn_global_load_lds(AS1C(Bw + (size_t)(n0 + row) * K + k0 + gch * 8),
                                             AS3(&Bs[c * 8]), 16, 0, 0);
        }
        __syncthreads();
#pragma unroll
        for (int ks = 0; ks < 2; ++ks) {
            bf16x8 af[4], bfr[4];
#pragma unroll
            for (int rt = 0; rt < 4; ++rt)
                af[rt] = *reinterpret_cast<const bf16x8*>(
                    &As[(wr + rt * 16 + l15) * 64 + (((ks * 4 + quad) ^ rA) * 8)]);
#pragma unroll
            for (int ct = 0; ct < 4; ++ct)
                bfr[ct] = *reinterpret_cast<const bf16x8*>(
                    &Bs[(wc + ct * 16 + l15) * 64 + (((ks * 4 + quad) ^ rA) * 8)]);
#pragma unroll
            for (int ct = 0; ct < 4; ++ct)
#pragma unroll
                for (int rt = 0; rt < 4; ++rt)
                    acc[ct][rt] = __builtin_amdgcn_mfma_f32_16x16x32_bf16(bfr[ct], af[rt], acc[ct][rt], 0, 0, 0);
        }
    }

    // C[m0+wr+rt*16+l15][n0+wc+ct*16+quad*4+reg] = acc[ct][rt][reg] + bias
#pragma unroll
    for (int ct = 0; ct < 4; ++ct) {
        int col = n0 + wc + ct * 16 + quad * 4;
        float4 bv = *reinterpret_cast<const float4*>(cbias + col);
#pragma unroll
        for (int rt = 0; rt < 4; ++rt) {
            int row = m0 + wr + rt * 16 + l15;
            float4 ov;
            ov.x = acc[ct][rt][0] + bv.x;
            ov.y = acc[ct][rt][1] + bv.y;
            ov.z = acc[ct][rt][2] + bv.z;
            ov.w = acc[ct][rt][3] + bv.w;
            *reinterpret_cast<float4*>(C + (size_t)row * Nn + col) = ov;
        }
    }
}

// ---------------------------------------------------------------------------
// Flash attention v7 (EXACT revert to the 102us R2 config): swapped QK^T
// (S^T = mfma(K,Q)) -> packed ds_write_b64 P-store; bias along-j uint2;
// double-buffered K/V via global_load_lds, one barrier per j-tile;
// 4 waves/block, 1024 blocks (3/CU). Grid x=h for XCD locality.
// ---------------------------------------------------------------------------
__global__ __launch_bounds__(256, 3) void flash_attn(const unsigned short* __restrict__ qkv,
                                                     const unsigned short* __restrict__ vt,
                                                     const uint32_t* __restrict__ biast,
                                                     unsigned short* __restrict__ aout) {
    __shared__ unsigned short Kb[2][64 * 64];
    __shared__ unsigned short Vb[2][64 * 64];
    __shared__ __align__(16) unsigned short Ps[4 * 32 * 72];
    const int tid  = threadIdx.x;
    const int lane = tid & 63, w = tid >> 6;
    const int l15  = lane & 15, quad = lane >> 4;
    const int h = blockIdx.x, qt = blockIdx.y, b = blockIdx.z;   // x=h: XCD locality
    const int i0 = qt * 128 + w * 32;
    const float kscale = 0.125f * LOG2E;
    const int l7 = l15 & 7;

    // Q fragments: A[m=lane&15][k=quad*8+j]
    bf16x8 qf[2][2];
#pragma unroll
    for (int rt = 0; rt < 2; ++rt)
#pragma unroll
        for (int ks = 0; ks < 2; ++ks)
            qf[rt][ks] = *reinterpret_cast<const bf16x8*>(
                qkv + (size_t)(b * 1024 + i0 + rt * 16 + l15) * 1536 + h * 64 + ks * 32 + quad * 8);

    f32x4 o[2][4];
    f32x4 lacc[2];
#pragma unroll
    for (int rt = 0; rt < 2; ++rt) {
#pragma unroll
        for (int nt = 0; nt < 4; ++nt) { o[rt][nt][0] = 0.f; o[rt][nt][1] = 0.f; o[rt][nt][2] = 0.f; o[rt][nt][3] = 0.f; }
        lacc[rt][0] = 0.f; lacc[rt][1] = 0.f; lacc[rt][2] = 0.f; lacc[rt][3] = 0.f;
    }

    bf16x8 ones;
#pragma unroll
    for (int e = 0; e < 8; ++e) ones[e] = (short)0x3F80;   // bf16 1.0

    const int srow = lane >> 3;
    const int gch  = (lane & 7) ^ srow;
    const unsigned short* kgbase = qkv + (size_t)b * 1024 * 1536 + 512 + h * 64 + gch * 8;
    const unsigned short* vgbase = vt + (size_t)((b * 8 + h) * 64) * 1024 + gch * 8;
    // bias base: biast_u32[(h*1024 + i)*512 + (j>>1)]; this warp's query rows
    const uint32_t* bb = biast + ((size_t)h * 1024 + i0) * 512;
    unsigned short* ps = &Ps[w * 32 * 72];

    // prologue: stage tile 0 into buffer 0
#pragma unroll
    for (int t = 0; t < 2; ++t) {
        int rl = w * 16 + t * 8 + srow;
        __builtin_amdgcn_global_load_lds(AS1C(kgbase + (size_t)rl * 1536),
                                         AS3(&Kb[0][(w * 16 + t * 8) * 64]), 16, 0, 0);
        __builtin_amdgcn_global_load_lds(AS1C(vgbase + (size_t)rl * 1024),
                                         AS3(&Vb[0][(w * 16 + t * 8) * 64]), 16, 0, 0);
    }

#pragma unroll 2
    for (int it = 0; it < 16; ++it) {
        const int cur = it & 1, nxt = cur ^ 1;
        const int j0 = it * 64;
        __syncthreads();   // drains prefetch (issued a full compute phase ago); frees buf[nxt]

        if (it < 15) {
            const int j0n = j0 + 64;
#pragma unroll
            for (int t = 0; t < 2; ++t) {
                int rl = w * 16 + t * 8 + srow;
                __builtin_amdgcn_global_load_lds(AS1C(kgbase + (size_t)(j0n + rl) * 1536),
                                                 AS3(&Kb[nxt][(w * 16 + t * 8) * 64]), 16, 0, 0);
                __builtin_amdgcn_global_load_lds(AS1C(vgbase + (size_t)rl * 1024 + j0n),
                                                 AS3(&Vb[nxt][(w * 16 + t * 8) * 64]), 16, 0, 0);
            }
        }

        // bias: uint2 = 4 fp16 along-j for query (rt*16+l15), keys j0+jt*16+quad*4..+3
        uint2 bl[2][4];
#pragma unroll
        for (int rt = 0; rt < 2; ++rt)
#pragma unroll
            for (int jt = 0; jt < 4; ++jt)
                bl[rt][jt] = *reinterpret_cast<const uint2*>(
                    bb + (size_t)(rt * 16 + l15) * 512 + (j0 >> 1) + jt * 8 + quad * 2);

        // S^T = K Q^T: D[key = quad*4+reg (+jt*16)][query = l15 (+rt*16)]
        f32x4 s[2][4];
#pragma unroll
        for (int rt = 0; rt < 2; ++rt)
#pragma unroll
            for (int jt = 0; jt < 4; ++jt) { s[rt][jt][0] = 0.f; s[rt][jt][1] = 0.f; s[rt][jt][2] = 0.f; s[rt][jt][3] = 0.f; }
#pragma unroll
        for (int ks = 0; ks < 2; ++ks) {
            bf16x8 kf[4];
#pragma unroll
            for (int jt = 0; jt < 4; ++jt)
                kf[jt] = *reinterpret_cast<const bf16x8*>(
                    &Kb[cur][(jt * 16 + l15) * 64 + (((ks * 4 + quad) ^ l7) * 8)]);
#pragma unroll
            for (int rt = 0; rt < 2; ++rt)
#pragma unroll
                for (int jt = 0; jt < 4; ++jt)
                    s[rt][jt] = __builtin_amdgcn_mfma_f32_16x16x32_bf16(kf[jt], qf[rt][ks], s[rt][jt], 0, 0, 0);
        }

        // p = exp2(s*kscale + bias); pack 4 consecutive-key bf16 -> 1 ds_write_b64
#pragma unroll
        for (int rt = 0; rt < 2; ++rt)
#pragma unroll
            for (int jt = 0; jt < 4; ++jt) {
                float2 f0 = __half22float2(__builtin_bit_cast(__half2, bl[rt][jt].x));
                float2 f1 = __half22float2(__builtin_bit_cast(__half2, bl[rt][jt].y));
                float p0 = fast_exp2(__builtin_fmaf(s[rt][jt][0], kscale, f0.x));
                float p1 = fast_exp2(__builtin_fmaf(s[rt][jt][1], kscale, f0.y));
                float p2 = fast_exp2(__builtin_fmaf(s[rt][jt][2], kscale, f1.x));
                float p3 = fast_exp2(__builtin_fmaf(s[rt][jt][3], kscale, f1.y));
                uint32_t u0 = (uint32_t)f32_to_bf16(p0) | ((uint32_t)f32_to_bf16(p1) << 16);
                uint32_t u1 = (uint32_t)f32_to_bf16(p2) | ((uint32_t)f32_to_bf16(p3) << 16);
                uint2 pk; pk.x = u0; pk.y = u1;
                *reinterpret_cast<uint2*>(ps + (rt * 16 + l15) * 72 + jt * 16 + quad * 4) = pk;
            }

        // PV + row-sum (same-wave Ps round trip; no barrier needed)
#pragma unroll
        for (int ks = 0; ks < 2; ++ks) {
            bf16x8 pf[2], vf[4];
#pragma unroll
            for (int rt = 0; rt < 2; ++rt)
                pf[rt] = *reinterpret_cast<const bf16x8*>(ps + (rt * 16 + l15) * 72 + ks * 32 + quad * 8);
#pragma unroll
            for (int nt = 0; nt < 4; ++nt)
                vf[nt] = *reinterpret_cast<const bf16x8*>(
                    &Vb[cur][(nt * 16 + l15) * 64 + (((ks * 4 + quad) ^ l7) * 8)]);
#pragma unroll
            for (int rt = 0; rt < 2; ++rt) {
#pragma unroll
                for (int nt = 0; nt < 4; ++nt)
                    o[rt][nt] = __builtin_amdgcn_mfma_f32_16x16x32_bf16(pf[rt], vf[nt], o[rt][nt], 0, 0, 0);
                lacc[rt] = __builtin_amdgcn_mfma_f32_16x16x32_bf16(pf[rt], ones, lacc[rt], 0, 0, 0);
            }
        }
    }

    // finalize
#pragma unroll
    for (int rt = 0; rt < 2; ++rt) {
        float inv[4];
#pragma unroll
        for (int reg = 0; reg < 4; ++reg) inv[reg] = 1.f / lacc[rt][reg];
#pragma unroll
        for (int nt = 0; nt < 4; ++nt)
#pragma unroll
            for (int reg = 0; reg < 4; ++reg) {
                int row = b * 1024 + i0 + rt * 16 + quad * 4 + reg;
                int col = h * 64 + nt * 16 + l15;
                aout[(size_t)row * 512 + col] = f32_to_bf16(o[rt][nt][reg] * inv[reg]);
            }
    }
}

// ---------------------------------------------------------------------------
extern "C" void kernel_launch(void* const* d_in, const int* in_sizes, int n_in,
                              void* d_out, int out_size, void* d_ws, size_t ws_size,
                              hipStream_t stream) {
    const float* x          = (const float*)d_in[0];
    const float* Hstack     = (const float*)d_in[1];
    const float* hop_logits = (const float*)d_in[2];
    const float* rel_alpha  = (const float*)d_in[3];
    const float* Wqkv       = (const float*)d_in[4];
    const float* Wproj      = (const float*)d_in[5];
    const float* bproj      = (const float*)d_in[6];
    float* out = (float*)d_out;

    char* ws = (char*)d_ws;
    unsigned short* xb    = (unsigned short*)(ws);                  // x bf16        16 MB
    unsigned short* wqb   = (unsigned short*)(ws + 16777216);       // Wqkv bf16    1.5 MB
    unsigned short* wpb   = (unsigned short*)(ws + 18350080);       // Wproj bf16   0.5 MB
    unsigned short* qkvb  = (unsigned short*)(ws + 18874368);       // qkv bf16 (Q,K used)  48 MB
    unsigned short* vtb   = (unsigned short*)(ws + 69206016);       // V^T bf16      16 MB
    uint32_t*       biast = (uint32_t*)(ws + 85983232);             // bias fp16 [h][i][j/2] 16 MB
    unsigned short* aoutb = (unsigned short*)(ws + 102760448);      // attn out bf16 16 MB

    // 1. merged converts + hop-bias (one dispatch)
    cvt_bias<<<9472, 256, 0, stream>>>(x, Wqkv, Wproj, Hstack, hop_logits, rel_alpha,
                                       xb, wqb, wpb, biast);

    // 2. qkv GEMM (BK=64, swizzled, vectorized epilogue); V transposed into vt
    gemm_qkv<<<1536, 256, 0, stream>>>(xb, wqb, qkvb, vtb);

    // 3. flash attention (v7 exact) -> [B,N,512] bf16
    flash_attn<<<dim3(8, 8, 16), 256, 0, stream>>>(qkvb, vtb, biast, aoutb);

    // 4. out = attn_out @ Wproj^T + bproj (BK=64, swizzled, float4 epilogue)
    gemm_proj<<<512, 256, 0, stream>>>(aoutb, wpb, out, bproj);
}

// Round 10
// 266.911 us; speedup vs baseline: 1.1452x; 1.0304x over previous
//
#include <hip/hip_runtime.h>
#include <hip/hip_bf16.h>
#include <hip/hip_fp16.h>
#include <stdint.h>

// Problem constants (from reference)
#define DIM   512
#define NH    8
#define HD    64
#define NB    16
#define NTOK  1024
#define KHOPS 5

typedef __attribute__((ext_vector_type(8))) short bf16x8;   // 8 bf16 = 4 VGPR
typedef __attribute__((ext_vector_type(4))) float f32x4;

#define LOG2E 1.4426950408889634f

__device__ __forceinline__ unsigned short f32_to_bf16(float f) {
    unsigned int u = __builtin_bit_cast(unsigned int, f);
    unsigned int r = (u + 0x7FFFu + ((u >> 16) & 1u)) >> 16;   // RNE
    return (unsigned short)r;
}

__device__ __forceinline__ float fast_exp2(float x) {
    return __builtin_amdgcn_exp2f(x);
}

#define AS1C(p) ((const __attribute__((address_space(1))) void*)(p))
#define AS3(p)  ((__attribute__((address_space(3))) void*)(p))

// ---------------------------------------------------------------------------
// merged fp32 -> bf16 converts: x (8192 blocks), Wqkv (768), Wproj (256)
// (exact R2 config -- best measured non-flash pipeline)
// ---------------------------------------------------------------------------
__global__ __launch_bounds__(256) void cvt_all(const float* __restrict__ x,
                                               const float* __restrict__ wq,
                                               const float* __restrict__ wp,
                                               unsigned short* __restrict__ xb,
                                               unsigned short* __restrict__ wqb,
                                               unsigned short* __restrict__ wpb) {
    int bid = blockIdx.x;
    const float* in; unsigned short* out; int i;
    if (bid < 8192)      { in = x;  out = xb;  i = bid * 256 + threadIdx.x; }
    else if (bid < 8960) { in = wq; out = wqb; i = (bid - 8192) * 256 + threadIdx.x; }
    else                 { in = wp; out = wpb; i = (bid - 8960) * 256 + threadIdx.x; }
    float4 v = reinterpret_cast<const float4*>(in)[i];
    ushort4 o;
    o.x = f32_to_bf16(v.x); o.y = f32_to_bf16(v.y);
    o.z = f32_to_bf16(v.z); o.w = f32_to_bf16(v.w);
    reinterpret_cast<ushort4*>(out)[i] = o;
}

// ---------------------------------------------------------------------------
// Fused hop-bias, ALL 8 HEADS per block (exact R2 config). Along-j fp16 pairs:
//   biast_u32[(h*1024 + i)*512 + (j>>1)] = half2(bias[i][j], bias[i][j+1])
// ---------------------------------------------------------------------------
__global__ __launch_bounds__(256) void bias_fused(const float* __restrict__ H,
                                                  const float* __restrict__ hop_logits,
                                                  const float* __restrict__ rel_alpha,
                                                  uint32_t* __restrict__ biast) {
    const int tid = threadIdx.x;
    const int jt = blockIdx.x, it = blockIdx.y;
    const int j0 = jt * 64, i0 = it * 64;
    float cf[NH][KHOPS];
#pragma unroll
    for (int h = 0; h < NH; ++h) {
        float m = -1e30f;
#pragma unroll
        for (int k = 0; k < KHOPS; ++k) m = fmaxf(m, hop_logits[h * KHOPS + k]);
        float s = 0.f;
#pragma unroll
        for (int k = 0; k < KHOPS; ++k) { cf[h][k] = fast_exp2((hop_logits[h * KHOPS + k] - m) * LOG2E); s += cf[h][k]; }
        float ra = rel_alpha[h] * LOG2E / s;
#pragma unroll
        for (int k = 0; k < KHOPS; ++k) cf[h][k] *= ra;
    }
    const int r = tid >> 2, c0 = (tid & 3) * 16;
    float hv[KHOPS][16];
#pragma unroll
    for (int k = 0; k < KHOPS; ++k) {
        const float4* src = reinterpret_cast<const float4*>(
            H + (size_t)k * 1048576 + (size_t)(i0 + r) * 1024 + j0 + c0);
#pragma unroll
        for (int q = 0; q < 4; ++q) {
            float4 v = src[q];
            hv[k][q * 4 + 0] = v.x; hv[k][q * 4 + 1] = v.y;
            hv[k][q * 4 + 2] = v.z; hv[k][q * 4 + 3] = v.w;
        }
    }
    for (int h = 0; h < NH; ++h) {
        uint32_t buf[8];
#pragma unroll
        for (int q = 0; q < 4; ++q) {
            float a0 = 0.f, a1 = 0.f, a2 = 0.f, a3 = 0.f;
#pragma unroll
            for (int k = 0; k < KHOPS; ++k) {
                a0 += cf[h][k] * hv[k][q * 4 + 0];
                a1 += cf[h][k] * hv[k][q * 4 + 1];
                a2 += cf[h][k] * hv[k][q * 4 + 2];
                a3 += cf[h][k] * hv[k][q * 4 + 3];
            }
            buf[q * 2 + 0] = __builtin_bit_cast(uint32_t, __floats2half2_rn(a0, a1));
            buf[q * 2 + 1] = __builtin_bit_cast(uint32_t, __floats2half2_rn(a2, a3));
        }
        uint32_t* dst = biast + ((size_t)h * 1024 + i0 + r) * 512 + ((j0 + c0) >> 1);
        uint4 w0; w0.x = buf[0]; w0.y = buf[1]; w0.z = buf[2]; w0.w = buf[3];
        uint4 w1; w1.x = buf[4]; w1.y = buf[5]; w1.z = buf[6]; w1.w = buf[7];
        reinterpret_cast<uint4*>(dst)[0] = w0;
        reinterpret_cast<uint4*>(dst)[1] = w1;
    }
}

// ---------------------------------------------------------------------------
// gemm_qkv (exact R2 v1): BK=32, 2-barrier, XCD-partitioned. V transposed.
// ---------------------------------------------------------------------------
__global__ __launch_bounds__(256) void gemm_qkv(const unsigned short* __restrict__ A,
                                                const unsigned short* __restrict__ Bw,
                                                unsigned short* __restrict__ qkv,
                                                unsigned short* __restrict__ vt) {
    __shared__ unsigned short As[128 * 32];
    __shared__ unsigned short Bs[128 * 32];
    const int tid  = threadIdx.x;
    const int lane = tid & 63;
    const int w    = tid >> 6;
    const int wr   = (w >> 1) * 64, wc = (w & 1) * 64;
    const int l15  = lane & 15, quad = lane >> 4;
    const int bid  = blockIdx.x;
    const int xcd  = bid & 7, slot = bid >> 3;
    const int m0   = (xcd * 16 + (slot & 15)) * 128;
    const int n0   = (slot >> 4) * 128;
    const int K = 512, Nn = 1536;

    f32x4 acc[4][4];
#pragma unroll
    for (int i = 0; i < 4; ++i)
#pragma unroll
        for (int j = 0; j < 4; ++j) { acc[i][j][0] = 0.f; acc[i][j][1] = 0.f; acc[i][j][2] = 0.f; acc[i][j][3] = 0.f; }

    for (int k0 = 0; k0 < K; k0 += 32) {
        __syncthreads();
#pragma unroll
        for (int t = 0; t < 2; ++t) {
            int c = t * 256 + w * 64 + lane;
            int r = c >> 2, kh = c & 3;
            const unsigned short* ga = A  + (size_t)(m0 + r) * K + k0 + kh * 8;
            const unsigned short* gb = Bw + (size_t)(n0 + r) * K + k0 + kh * 8;
            __builtin_amdgcn_global_load_lds(AS1C(ga), AS3(&As[(t * 256 + w * 64) * 8]), 16, 0, 0);
            __builtin_amdgcn_global_load_lds(AS1C(gb), AS3(&Bs[(t * 256 + w * 64) * 8]), 16, 0, 0);
        }
        __syncthreads();
        bf16x8 af[4], bfr[4];
#pragma unroll
        for (int rt = 0; rt < 4; ++rt)
            af[rt] = *reinterpret_cast<const bf16x8*>(&As[(wr + rt * 16 + l15) * 32 + quad * 8]);
#pragma unroll
        for (int ct = 0; ct < 4; ++ct)
            bfr[ct] = *reinterpret_cast<const bf16x8*>(&Bs[(wc + ct * 16 + l15) * 32 + quad * 8]);
#pragma unroll
        for (int rt = 0; rt < 4; ++rt)
#pragma unroll
            for (int ct = 0; ct < 4; ++ct)
                acc[rt][ct] = __builtin_amdgcn_mfma_f32_16x16x32_bf16(af[rt], bfr[ct], acc[rt][ct], 0, 0, 0);
    }

    if (n0 < 1024) {
        // Q/K: row-major bf16 into qkv
#pragma unroll
        for (int rt = 0; rt < 4; ++rt)
#pragma unroll
            for (int ct = 0; ct < 4; ++ct)
#pragma unroll
                for (int reg = 0; reg < 4; ++reg) {
                    int row = m0 + wr + rt * 16 + quad * 4 + reg;
                    int col = n0 + wc + ct * 16 + l15;
                    qkv[(size_t)row * Nn + col] = f32_to_bf16(acc[rt][ct][reg]);
                }
    } else {
        // V: transposed into vt[b][h][d][token]
        const int b = m0 >> 10;
#pragma unroll
        for (int ct = 0; ct < 4; ++ct) {
            int c = n0 - 1024 + wc + ct * 16 + l15;   // h*64+d
            unsigned short* vrow = vt + ((size_t)(b * 8) * 64 + c) * 1024;
#pragma unroll
            for (int rt = 0; rt < 4; ++rt) {
                int trow = (m0 & 1023) + wr + rt * 16 + quad * 4;
                ushort4 pk;
                pk.x = f32_to_bf16(acc[rt][ct][0]);
                pk.y = f32_to_bf16(acc[rt][ct][1]);
                pk.z = f32_to_bf16(acc[rt][ct][2]);
                pk.w = f32_to_bf16(acc[rt][ct][3]);
                *reinterpret_cast<ushort4*>(vrow + trow) = pk;
            }
        }
    }
}

// ---------------------------------------------------------------------------
// gemm_proj (exact R2 v1): BK=32, 2-barrier, XCD-partitioned. fp32 out + bias.
// ---------------------------------------------------------------------------
__global__ __launch_bounds__(256) void gemm_proj(const unsigned short* __restrict__ A,
                                                 const unsigned short* __restrict__ Bw,
                                                 float* __restrict__ C,
                                                 const float* __restrict__ cbias) {
    __shared__ unsigned short As[128 * 32];
    __shared__ unsigned short Bs[128 * 32];
    const int tid  = threadIdx.x;
    const int lane = tid & 63;
    const int w    = tid >> 6;
    const int wr   = (w >> 1) * 64, wc = (w & 1) * 64;
    const int l15  = lane & 15, quad = lane >> 4;
    const int bid  = blockIdx.x;
    const int xcd  = bid & 7, slot = bid >> 3;
    const int m0   = (xcd * 16 + (slot & 15)) * 128;
    const int n0   = (slot >> 4) * 128;
    const int K = 512, Nn = 512;

    f32x4 acc[4][4];
#pragma unroll
    for (int i = 0; i < 4; ++i)
#pragma unroll
        for (int j = 0; j < 4; ++j) { acc[i][j][0] = 0.f; acc[i][j][1] = 0.f; acc[i][j][2] = 0.f; acc[i][j][3] = 0.f; }

    for (int k0 = 0; k0 < K; k0 += 32) {
        __syncthreads();
#pragma unroll
        for (int t = 0; t < 2; ++t) {
            int c = t * 256 + w * 64 + lane;
            int r = c >> 2, kh = c & 3;
            const unsigned short* ga = A  + (size_t)(m0 + r) * K + k0 + kh * 8;
            const unsigned short* gb = Bw + (size_t)(n0 + r) * K + k0 + kh * 8;
            __builtin_amdgcn_global_load_lds(AS1C(ga), AS3(&As[(t * 256 + w * 64) * 8]), 16, 0, 0);
            __builtin_amdgcn_global_load_lds(AS1C(gb), AS3(&Bs[(t * 256 + w * 64) * 8]), 16, 0, 0);
        }
        __syncthreads();
        bf16x8 af[4], bfr[4];
#pragma unroll
        for (int rt = 0; rt < 4; ++rt)
            af[rt] = *reinterpret_cast<const bf16x8*>(&As[(wr + rt * 16 + l15) * 32 + quad * 8]);
#pragma unroll
        for (int ct = 0; ct < 4; ++ct)
            bfr[ct] = *reinterpret_cast<const bf16x8*>(&Bs[(wc + ct * 16 + l15) * 32 + quad * 8]);
#pragma unroll
        for (int rt = 0; rt < 4; ++rt)
#pragma unroll
            for (int ct = 0; ct < 4; ++ct)
                acc[rt][ct] = __builtin_amdgcn_mfma_f32_16x16x32_bf16(af[rt], bfr[ct], acc[rt][ct], 0, 0, 0);
    }

#pragma unroll
    for (int ct = 0; ct < 4; ++ct) {
        int col = n0 + wc + ct * 16 + l15;
        float bv = cbias[col];
#pragma unroll
        for (int rt = 0; rt < 4; ++rt)
#pragma unroll
            for (int reg = 0; reg < 4; ++reg) {
                int row = m0 + wr + rt * 16 + quad * 4 + reg;
                C[(size_t)row * Nn + col] = acc[rt][ct][reg] + bv;
            }
    }
}

// ---------------------------------------------------------------------------
// Flash attention v12: v7 semantics, 64 QUERIES PER WAVE (rt=0..3).
// flash is stall-bound (42% issue-busy, 58% all-waves-stalled): per j-tile
// each wave pays a fixed stall skeleton (kf lgkm, softmax VALU chain, Ps
// round-trip, pf lgkm, barrier) regardless of work. Doubling queries/wave
// doubles MFMA+VALU per skeleton: 72 MFMA + ~900 VALU per tile (was 36/~500).
// Grid (8,4,16) = 512 blocks = exactly 2/CU (LDS 64KB), single round.
// QK/softmax in rt-PAIRS (s[2][4] live, kf reloaded per pair) to keep
// VGPR peak ~230 under the (256,2) cap. Ps stride-64 XOR-swizzled (v9's
// verified swizzle; row&7 == l15&7 invariant holds for rt 0..3).
// ---------------------------------------------------------------------------
__global__ __launch_bounds__(256, 2) void flash_attn(const unsigned short* __restrict__ qkv,
                                                     const unsigned short* __restrict__ vt,
                                                     const uint32_t* __restrict__ biast,
                                                     unsigned short* __restrict__ aout) {
    __shared__ unsigned short Kb[2][64 * 64];
    __shared__ unsigned short Vb[2][64 * 64];
    __shared__ __align__(16) unsigned short Ps[4 * 64 * 64];
    const int tid  = threadIdx.x;
    const int lane = tid & 63, w = tid >> 6;
    const int l15  = lane & 15, quad = lane >> 4;
    const int h = blockIdx.x, qt = blockIdx.y, b = blockIdx.z;   // x=h: XCD locality
    const int i0 = qt * 256 + w * 64;                  // 4 waves x 64 queries
    const float kscale = 0.125f * LOG2E;
    const int l7 = l15 & 7;
    const int psw = l7 << 3;                           // Ps XOR swizzle (shorts)

    // Q fragments: A[m=lane&15][k=quad*8+j], rt 0..3
    bf16x8 qf[4][2];
#pragma unroll
    for (int rt = 0; rt < 4; ++rt)
#pragma unroll
        for (int ks = 0; ks < 2; ++ks)
            qf[rt][ks] = *reinterpret_cast<const bf16x8*>(
                qkv + (size_t)(b * 1024 + i0 + rt * 16 + l15) * 1536 + h * 64 + ks * 32 + quad * 8);

    f32x4 o[4][4];
    f32x4 lacc[4];
#pragma unroll
    for (int rt = 0; rt < 4; ++rt) {
#pragma unroll
        for (int nt = 0; nt < 4; ++nt) { o[rt][nt][0] = 0.f; o[rt][nt][1] = 0.f; o[rt][nt][2] = 0.f; o[rt][nt][3] = 0.f; }
        lacc[rt][0] = 0.f; lacc[rt][1] = 0.f; lacc[rt][2] = 0.f; lacc[rt][3] = 0.f;
    }

    bf16x8 ones;
#pragma unroll
    for (int e = 0; e < 8; ++e) ones[e] = (short)0x3F80;   // bf16 1.0

    const int srow = lane >> 3;
    const int gch  = (lane & 7) ^ srow;
    const unsigned short* kgbase = qkv + (size_t)b * 1024 * 1536 + 512 + h * 64 + gch * 8;
    const unsigned short* vgbase = vt + (size_t)((b * 8 + h) * 64) * 1024 + gch * 8;
    // bias base: biast_u32[(h*1024 + i)*512 + (j>>1)]; this wave's query rows
    const uint32_t* bb = biast + ((size_t)h * 1024 + i0) * 512;
    unsigned short* ps = &Ps[w * 64 * 64];

    // prologue: stage tile 0 into buffer 0 (4 waves cover 64 K-rows + 64 V-rows)
#pragma unroll
    for (int t = 0; t < 2; ++t) {
        int rl = w * 16 + t * 8 + srow;
        __builtin_amdgcn_global_load_lds(AS1C(kgbase + (size_t)rl * 1536),
                                         AS3(&Kb[0][(w * 16 + t * 8) * 64]), 16, 0, 0);
        __builtin_amdgcn_global_load_lds(AS1C(vgbase + (size_t)rl * 1024),
                                         AS3(&Vb[0][(w * 16 + t * 8) * 64]), 16, 0, 0);
    }

#pragma unroll 2
    for (int it = 0; it < 16; ++it) {
        const int cur = it & 1, nxt = cur ^ 1;
        const int j0 = it * 64;
        __syncthreads();   // drains prefetch (issued a full compute phase ago); frees buf[nxt]

        if (it < 15) {
            const int j0n = j0 + 64;
#pragma unroll
            for (int t = 0; t < 2; ++t) {
                int rl = w * 16 + t * 8 + srow;
                __builtin_amdgcn_global_load_lds(AS1C(kgbase + (size_t)(j0n + rl) * 1536),
                                                 AS3(&Kb[nxt][(w * 16 + t * 8) * 64]), 16, 0, 0);
                __builtin_amdgcn_global_load_lds(AS1C(vgbase + (size_t)rl * 1024 + j0n),
                                                 AS3(&Vb[nxt][(w * 16 + t * 8) * 64]), 16, 0, 0);
            }
        }

        // bias: uint2 = 4 fp16 along-j for query (rt*16+l15), keys j0+jt*16+quad*4..+3
        uint2 bl[4][4];
#pragma unroll
        for (int rt = 0; rt < 4; ++rt)
#pragma unroll
            for (int jt = 0; jt < 4; ++jt)
                bl[rt][jt] = *reinterpret_cast<const uint2*>(
                    bb + (size_t)(rt * 16 + l15) * 512 + (j0 >> 1) + jt * 8 + quad * 2);

        // S^T = K Q^T in rt-PAIRS: D[key = quad*4+reg (+jt*16)][query = l15 (+rt*16)]
#pragma unroll
        for (int rp = 0; rp < 2; ++rp) {
            f32x4 s[2][4];
#pragma unroll
            for (int r2 = 0; r2 < 2; ++r2)
#pragma unroll
                for (int jt = 0; jt < 4; ++jt) { s[r2][jt][0] = 0.f; s[r2][jt][1] = 0.f; s[r2][jt][2] = 0.f; s[r2][jt][3] = 0.f; }
#pragma unroll
            for (int ks = 0; ks < 2; ++ks) {
                bf16x8 kf[4];
#pragma unroll
                for (int jt = 0; jt < 4; ++jt)
                    kf[jt] = *reinterpret_cast<const bf16x8*>(
                        &Kb[cur][(jt * 16 + l15) * 64 + (((ks * 4 + quad) ^ l7) * 8)]);
#pragma unroll
                for (int r2 = 0; r2 < 2; ++r2)
#pragma unroll
                    for (int jt = 0; jt < 4; ++jt)
                        s[r2][jt] = __builtin_amdgcn_mfma_f32_16x16x32_bf16(kf[jt], qf[rp * 2 + r2][ks], s[r2][jt], 0, 0, 0);
            }
            // p = exp2(s*kscale + bias); pack 4 consecutive-key bf16 -> ds_write_b64
#pragma unroll
            for (int r2 = 0; r2 < 2; ++r2)
#pragma unroll
                for (int jt = 0; jt < 4; ++jt) {
                    const int rt = rp * 2 + r2;
                    float2 f0 = __half22float2(__builtin_bit_cast(__half2, bl[rt][jt].x));
                    float2 f1 = __half22float2(__builtin_bit_cast(__half2, bl[rt][jt].y));
                    float p0 = fast_exp2(__builtin_fmaf(s[r2][jt][0], kscale, f0.x));
                    float p1 = fast_exp2(__builtin_fmaf(s[r2][jt][1], kscale, f0.y));
                    float p2 = fast_exp2(__builtin_fmaf(s[r2][jt][2], kscale, f1.x));
                    float p3 = fast_exp2(__builtin_fmaf(s[r2][jt][3], kscale, f1.y));
                    uint32_t u0 = (uint32_t)f32_to_bf16(p0) | ((uint32_t)f32_to_bf16(p1) << 16);
                    uint32_t u1 = (uint32_t)f32_to_bf16(p2) | ((uint32_t)f32_to_bf16(p3) << 16);
                    uint2 pk; pk.x = u0; pk.y = u1;
                    *reinterpret_cast<uint2*>(
                        ps + (((rt * 16 + l15) * 64 + jt * 16 + quad * 4) ^ psw)) = pk;
                }
        }

        // PV + row-sum (same-wave Ps round trip; no barrier needed)
#pragma unroll
        for (int ks = 0; ks < 2; ++ks) {
            bf16x8 vf[4];
#pragma unroll
            for (int nt = 0; nt < 4; ++nt)
                vf[nt] = *reinterpret_cast<const bf16x8*>(
                    &Vb[cur][(nt * 16 + l15) * 64 + (((ks * 4 + quad) ^ l7) * 8)]);
#pragma unroll
            for (int rt = 0; rt < 4; ++rt) {
                bf16x8 pf = *reinterpret_cast<const bf16x8*>(
                    ps + (((rt * 16 + l15) * 64 + ks * 32 + quad * 8) ^ psw));
#pragma unroll
                for (int nt = 0; nt < 4; ++nt)
                    o[rt][nt] = __builtin_amdgcn_mfma_f32_16x16x32_bf16(pf, vf[nt], o[rt][nt], 0, 0, 0);
                lacc[rt] = __builtin_amdgcn_mfma_f32_16x16x32_bf16(pf, ones, lacc[rt], 0, 0, 0);
            }
        }
    }

    // finalize
#pragma unroll
    for (int rt = 0; rt < 4; ++rt) {
        float inv[4];
#pragma unroll
        for (int reg = 0; reg < 4; ++reg) inv[reg] = 1.f / lacc[rt][reg];
#pragma unroll
        for (int nt = 0; nt < 4; ++nt)
#pragma unroll
            for (int reg = 0; reg < 4; ++reg) {
                int row = b * 1024 + i0 + rt * 16 + quad * 4 + reg;
                int col = h * 64 + nt * 16 + l15;
                aout[(size_t)row * 512 + col] = f32_to_bf16(o[rt][nt][reg] * inv[reg]);
            }
    }
}

// ---------------------------------------------------------------------------
extern "C" void kernel_launch(void* const* d_in, const int* in_sizes, int n_in,
                              void* d_out, int out_size, void* d_ws, size_t ws_size,
                              hipStream_t stream) {
    const float* x          = (const float*)d_in[0];
    const float* Hstack     = (const float*)d_in[1];
    const float* hop_logits = (const float*)d_in[2];
    const float* rel_alpha  = (const float*)d_in[3];
    const float* Wqkv       = (const float*)d_in[4];
    const float* Wproj      = (const float*)d_in[5];
    const float* bproj      = (const float*)d_in[6];
    float* out = (float*)d_out;

    char* ws = (char*)d_ws;
    unsigned short* xb    = (unsigned short*)(ws);                  // x bf16        16 MB
    unsigned short* wqb   = (unsigned short*)(ws + 16777216);       // Wqkv bf16    1.5 MB
    unsigned short* wpb   = (unsigned short*)(ws + 18350080);       // Wproj bf16   0.5 MB
    unsigned short* qkvb  = (unsigned short*)(ws + 18874368);       // qkv bf16 (Q,K used)  48 MB
    unsigned short* vtb   = (unsigned short*)(ws + 69206016);       // V^T bf16      16 MB
    uint32_t*       biast = (uint32_t*)(ws + 85983232);             // bias fp16 [h][i][j/2] 16 MB
    unsigned short* aoutb = (unsigned short*)(ws + 102760448);      // attn out bf16 16 MB

    // 1. merged converts (exact R2)
    cvt_all<<<9216, 256, 0, stream>>>(x, Wqkv, Wproj, xb, wqb, wpb);

    // 2. fused hop-bias (exact R2)
    bias_fused<<<dim3(16, 16), 256, 0, stream>>>(Hstack, hop_logits, rel_alpha, biast);

    // 3. qkv GEMM (exact R2 v1); V written transposed into vt
    gemm_qkv<<<1536, 256, 0, stream>>>(xb, wqb, qkvb, vtb);

    // 4. flash attention v12 (64 queries/wave, 512 blocks = 2/CU)
    flash_attn<<<dim3(8, 4, 16), 256, 0, stream>>>(qkvb, vtb, biast, aoutb);

    // 5. out = attn_out @ Wproj^T + bproj (exact R2 v1)
    gemm_proj<<<512, 256, 0, stream>>>(aoutb, wpb, out, bproj);
}